// Round 4
// baseline (27988.422 us; speedup 1.0000x reference)
//
#include <hip/hip_runtime.h>
#include <cstdint>
#include <cstddef>

// ============================================================================
// Actor rollout, round 4: persistent megakernel (1 main launch + tiny init).
//  - 250 blocks x 256 threads, all-resident (<=1 block/CU), own grid barrier
//    via device-scope atomics (pattern validated by round-3 ticket spin).
//  - per step: [A] GRU via split-bf16 MFMA on interleaved virtual W (32 blks)
//              bar [B] 2 logits strips/blk, register-resident, publish
//              per-strip softmax/Gumbel partials  bar  [W] every block
//              reduces stats, normalizes its register tiles, writes dist ONCE
//              + probs cols; gru blocks compute next sampled locally.
//  - dist raw-z rewrite pass eliminated (saves ~4.2 GB HBM traffic).
// PRNG: JAX threefry2x32 partitionable (bit-exact, unchanged).
// ============================================================================

#define JAX_PARTITIONABLE 1

#define Bn 64
#define Tn 64
#define Vn 32000
#define Hn 512
#define En 256
#define NBLK 250
#define NSTRIP 500

typedef unsigned short u16;
typedef __attribute__((ext_vector_type(8))) __bf16 bf16x8;
typedef __attribute__((ext_vector_type(4))) float f32x4;
typedef __attribute__((ext_vector_type(4))) uint32_t u32x4;

// ---------------- output layout (floats) ----------------
#define OUT_SAMP 0
#define OUT_CORR (Bn * Tn)
#define OUT_LOGP (2 * Bn * Tn)
#define OUT_DIST (3 * Bn * Tn)
#define OUT_PROB (3 * Bn * Tn + (size_t)Bn * Tn * Vn)

// ---------------- ws layout (float offsets) ----------------
#define WS_HT  0                          // 2 * Hn*64 f32 (hT[k][b], dbuf)
#define WS_HS  (2 * Hn * 64)              // 2*3*Bn*Hn u16 = 3*Bn*Hn floats
#define WS_PM  (WS_HS + 3 * Bn * Hn)      // [strip][row] f32
#define WS_PS  (WS_PM + NSTRIP * Bn)
#define WS_PBS (WS_PS + NSTRIP * Bn)
#define WS_PBV (WS_PBS + NSTRIP * Bn)     // int
#define WS_PBZ (WS_PBV + NSTRIP * Bn)
#define WS_BAR (WS_PBZ + NSTRIP * Bn)     // int

// ---------------- threefry2x32 (Random123 / JAX schedule) ----------------
__device__ __forceinline__ void tf2x32(uint32_t k0, uint32_t k1,
                                       uint32_t x0, uint32_t x1,
                                       uint32_t& o0, uint32_t& o1) {
  uint32_t ks2 = k0 ^ k1 ^ 0x1BD11BDAu;
  x0 += k0; x1 += k1;
#define TFR(r) { x0 += x1; x1 = (x1 << r) | (x1 >> (32 - r)); x1 ^= x0; }
  TFR(13) TFR(15) TFR(26) TFR(6)  x0 += k1;  x1 += ks2 + 1u;
  TFR(17) TFR(29) TFR(16) TFR(24) x0 += ks2; x1 += k0 + 2u;
  TFR(13) TFR(15) TFR(26) TFR(6)  x0 += k0;  x1 += k1 + 3u;
  TFR(17) TFR(29) TFR(16) TFR(24) x0 += k1;  x1 += ks2 + 4u;
  TFR(13) TFR(15) TFR(26) TFR(6)  x0 += ks2; x1 += k0 + 5u;
#undef TFR
  o0 = x0; o1 = x1;
}

__device__ __forceinline__ uint32_t jax_bits32(uint32_t k0, uint32_t k1,
                                               uint32_t i) {
  uint32_t o0, o1; tf2x32(k0, k1, 0u, i, o0, o1); return o0 ^ o1;
}

__device__ __forceinline__ void jax_splitkey(uint32_t k0, uint32_t k1,
                                             uint32_t idx,
                                             uint32_t& s0, uint32_t& s1) {
  tf2x32(k0, k1, 0u, idx, s0, s1);
}

__device__ __forceinline__ float bits_to_unit(uint32_t bits) {
  return __uint_as_float((bits >> 9) | 0x3F800000u) - 1.0f;
}

// ---------------- f32 -> 3x bf16 split (truncation; residual <= 2^-21) ----
struct Limbs3 { uint32_t p0, p1, p2; };

__device__ __forceinline__ Limbs3 split3_pair(float xa, float xb) {
  const uint32_t a0 = __float_as_uint(xa) & 0xFFFF0000u;
  const float ar1 = xa - __uint_as_float(a0);
  const uint32_t a1 = __float_as_uint(ar1) & 0xFFFF0000u;
  const float ar2 = ar1 - __uint_as_float(a1);
  const uint32_t a2 = __float_as_uint(ar2) & 0xFFFF0000u;
  const uint32_t b0 = __float_as_uint(xb) & 0xFFFF0000u;
  const float br1 = xb - __uint_as_float(b0);
  const uint32_t b1 = __float_as_uint(br1) & 0xFFFF0000u;
  const float br2 = br1 - __uint_as_float(b1);
  const uint32_t b2 = __float_as_uint(br2) & 0xFFFF0000u;
  Limbs3 r;
  r.p0 = (a0 >> 16) | b0;
  r.p1 = (a1 >> 16) | b1;
  r.p2 = (a2 >> 16) | b2;
  return r;
}

__device__ __forceinline__ void split3_frag(const float4& x0, const float4& x1,
                                            uint32_t msk,
                                            bf16x8& f0, bf16x8& f1, bf16x8& f2) {
  u32x4 q0, q1, q2;
  const Limbs3 l0 = split3_pair(x0.x, x0.y);
  const Limbs3 l1 = split3_pair(x0.z, x0.w);
  const Limbs3 l2 = split3_pair(x1.x, x1.y);
  const Limbs3 l3 = split3_pair(x1.z, x1.w);
  q0[0] = l0.p0 & msk; q1[0] = l0.p1 & msk; q2[0] = l0.p2 & msk;
  q0[1] = l1.p0 & msk; q1[1] = l1.p1 & msk; q2[1] = l1.p2 & msk;
  q0[2] = l2.p0 & msk; q1[2] = l2.p1 & msk; q2[2] = l2.p2 & msk;
  q0[3] = l3.p0 & msk; q1[3] = l3.p1 & msk; q2[3] = l3.p2 & msk;
  f0 = __builtin_bit_cast(bf16x8, q0);
  f1 = __builtin_bit_cast(bf16x8, q1);
  f2 = __builtin_bit_cast(bf16x8, q2);
}

__device__ __forceinline__ f32x4 mfma6(const bf16x8& a0, const bf16x8& a1,
                                       const bf16x8& a2, const bf16x8& b0,
                                       const bf16x8& b1, const bf16x8& b2,
                                       f32x4 c) {
  c = __builtin_amdgcn_mfma_f32_16x16x32_bf16(a0, b0, c, 0, 0, 0);
  c = __builtin_amdgcn_mfma_f32_16x16x32_bf16(a0, b1, c, 0, 0, 0);
  c = __builtin_amdgcn_mfma_f32_16x16x32_bf16(a1, b0, c, 0, 0, 0);
  c = __builtin_amdgcn_mfma_f32_16x16x32_bf16(a1, b1, c, 0, 0, 0);
  c = __builtin_amdgcn_mfma_f32_16x16x32_bf16(a0, b2, c, 0, 0, 0);
  c = __builtin_amdgcn_mfma_f32_16x16x32_bf16(a2, b0, c, 0, 0, 0);
  return c;
}

// ---------------- grid barrier (all blocks resident by construction) ------
__device__ __forceinline__ void gridbar(int* bar, int target) {
  __syncthreads();
  if (threadIdx.x == 0) {
    __threadfence();
    __hip_atomic_fetch_add(bar, 1, __ATOMIC_ACQ_REL, __HIP_MEMORY_SCOPE_AGENT);
    while (__hip_atomic_load(bar, __ATOMIC_ACQUIRE,
                             __HIP_MEMORY_SCOPE_AGENT) < target) {
      __builtin_amdgcn_s_sleep(1);
    }
  }
  __syncthreads();
  __threadfence();
}

// ---------------- init ----------------
__global__ void init_k(float* hT, uint32_t* hsw, int* bar) {
  const int i = blockIdx.x * 256 + threadIdx.x;
  if (i < 2 * Hn * 64) hT[i] = 0.0f;
  if (i < 3 * Bn * Hn) hsw[i] = 0u;   // 2*3*Bn*Hn u16 = 3*Bn*Hn u32
  if (i == 0) *bar = 0;
}

// ---------------- megakernel ----------------
__global__ __launch_bounds__(256, 2) void mega(
    const float* __restrict__ emb,
    const float* __restrict__ w_ih, const float* __restrict__ b_ih,
    const float* __restrict__ w_hh, const float* __restrict__ b_hh,
    const float* __restrict__ w_out, const float* __restrict__ b_out,
    float* __restrict__ out,
    float* __restrict__ hT, u16* __restrict__ hs,
    float* __restrict__ pM, float* __restrict__ pS, float* __restrict__ pBS,
    int* __restrict__ pBV, float* __restrict__ pBZ, int* __restrict__ bar) {
  const int blk = blockIdx.x;
  const int tid = threadIdx.x;
  const int w = tid >> 6;
  const int lane = tid & 63;
  const int wm = (w >> 1) * 32;
  const int wn = (w & 1) * 32;
  const int lr = lane & 15;
  const int lg = lane >> 4;
  const bool isGru = (blk < 32);
  const float LU = -logf((float)Vn);

  __shared__ float s_m[64], s_l[64];
  __shared__ int s_smp[64];
  __shared__ int s_dr[64];
  __shared__ float ldsM[64][2], ldsS[64][2], ldsBS[64][2], ldsBZ[64][2];
  __shared__ int ldsBV[64][2];
  __shared__ float Gs[64][66];
  __shared__ float pc[2][64];

  if (tid < 64) s_smp[tid] = 0;
  __syncthreads();

  // --- GRU per-lane virtual-W row precompute (interleaved col C = 4*j+gate)
  const float* gruIh[2];
  const float* gruHh[2];
  float gruBias[2];
  uint32_t gruMih[2], gruMhh[2];
  if (isGru) {
#pragma unroll
    for (int ni = 0; ni < 2; ni++) {
      const int C = blk * 64 + wn + ni * 16 + lr;
      const int gate = C & 3, j = C >> 2;
      int ihRow = j, hhRow = j;
      uint32_t mih = 0xFFFFFFFFu, mhh = 0xFFFFFFFFu;
      float bias;
      if (gate == 0)      { bias = b_ih[j] + b_hh[j]; }
      else if (gate == 1) { ihRow = 512 + j; hhRow = 512 + j;
                            bias = b_ih[512 + j] + b_hh[512 + j]; }
      else if (gate == 2) { ihRow = 1024 + j; hhRow = 0; mhh = 0u;
                            bias = b_ih[1024 + j]; }
      else                { ihRow = 0; mih = 0u; hhRow = 1024 + j;
                            bias = b_hh[1024 + j]; }
      gruIh[ni] = w_ih + (size_t)ihRow * En;
      gruHh[ni] = w_hh + (size_t)hhRow * Hn;
      gruMih[ni] = mih; gruMhh[ni] = mhh; gruBias[ni] = bias;
    }
  }

  int syncno = 0;

  for (int t = 0; t < Tn; t++) {
    const u16* hsPrev = hs + (size_t)((t + 1) & 1) * (3 * Bn * Hn);
    u16* hsCur = hs + (size_t)(t & 1) * (3 * Bn * Hn);
    const float* hTprev = hT + (size_t)((t + 1) & 1) * (Hn * 64);
    float* hTcur = hT + (size_t)(t & 1) * (Hn * 64);

    // ================= phase A: GRU (blocks 0..31) =================
    if (isGru) {
      f32x4 gacc[2][2] = {};
      for (int k0 = 0; k0 < En + Hn; k0 += 32) {
        bf16x8 a0[2], a1[2], a2[2];
        if (k0 < En) {
#pragma unroll
          for (int mi = 0; mi < 2; mi++) {
            const int b = wm + mi * 16 + lr;
            const float* sp = emb + (size_t)s_smp[b] * En + k0 + lg * 8;
            const float4 x0 = *(const float4*)sp;
            const float4 x1 = *(const float4*)(sp + 4);
            split3_frag(x0, x1, 0xFFFFFFFFu, a0[mi], a1[mi], a2[mi]);
          }
        } else {
#pragma unroll
          for (int mi = 0; mi < 2; mi++) {
            const int b = wm + mi * 16 + lr;
            const u16* hp = hsPrev + (size_t)b * Hn + (k0 - En) + lg * 8;
            a0[mi] = *(const bf16x8*)(hp);
            a1[mi] = *(const bf16x8*)(hp + Bn * Hn);
            a2[mi] = *(const bf16x8*)(hp + 2 * Bn * Hn);
          }
        }
        bf16x8 b0f[2], b1f[2], b2f[2];
#pragma unroll
        for (int ni = 0; ni < 2; ni++) {
          const float* sp;
          uint32_t msk;
          if (k0 < En) { sp = gruIh[ni] + k0 + lg * 8; msk = gruMih[ni]; }
          else         { sp = gruHh[ni] + (k0 - En) + lg * 8; msk = gruMhh[ni]; }
          const float4 x0 = *(const float4*)sp;
          const float4 x1 = *(const float4*)(sp + 4);
          split3_frag(x0, x1, msk, b0f[ni], b1f[ni], b2f[ni]);
        }
#pragma unroll
        for (int mi = 0; mi < 2; mi++)
#pragma unroll
          for (int ni = 0; ni < 2; ni++)
            gacc[mi][ni] = mfma6(a0[mi], a1[mi], a2[mi],
                                 b0f[ni], b1f[ni], b2f[ni], gacc[mi][ni]);
      }
      // epilogue: G into LDS (col-major over b), then gates
#pragma unroll
      for (int mi = 0; mi < 2; mi++)
#pragma unroll
        for (int ni = 0; ni < 2; ni++)
#pragma unroll
          for (int r = 0; r < 4; r++)
            Gs[wn + ni * 16 + lr][wm + mi * 16 + lg * 4 + r] =
                gacc[mi][ni][r] + gruBias[ni];
      __syncthreads();
#pragma unroll
      for (int u = 0; u < 4; u++) {
        const int p = tid + u * 256;
        const int jp = p >> 6, b = p & 63;
        const int jg = blk * 16 + jp;
        const float gr = Gs[4 * jp + 0][b], gz = Gs[4 * jp + 1][b];
        const float gin = Gs[4 * jp + 2][b], ghn = Gs[4 * jp + 3][b];
        const float rr = 1.0f / (1.0f + expf(-gr));
        const float zz = 1.0f / (1.0f + expf(-gz));
        const float nn = tanhf(gin + rr * ghn);
        const float hp = hTprev[jg * 64 + b];
        const float h = (1.0f - zz) * nn + zz * hp;
        hTcur[jg * 64 + b] = h;
        const uint32_t c0 = __float_as_uint(h) & 0xFFFF0000u;
        const float r1 = h - __uint_as_float(c0);
        const uint32_t c1 = __float_as_uint(r1) & 0xFFFF0000u;
        const float r2 = r1 - __uint_as_float(c1);
        const size_t ho = (size_t)b * Hn + jg;
        hsCur[ho] = (u16)(c0 >> 16);
        hsCur[Bn * Hn + ho] = (u16)(c1 >> 16);
        hsCur[2 * Bn * Hn + ho] = (u16)(__float_as_uint(r2) >> 16);
      }
    }
    gridbar(bar, (++syncno) * NBLK);   // h(t) limbs ready

    // ================= phase B: logits, strips 2*blk, 2*blk+1 ==========
    uint32_t kt0, kt1, kg0, kg1;
    jax_splitkey(0u, 1u, (uint32_t)t, kt0, kt1);
    jax_splitkey(kt0, kt1, 1u, kg0, kg1);
    if (tid < 64) {
      uint32_t ke0, ke1;
      jax_splitkey(kt0, kt1, 0u, ke0, ke1);
      const uint32_t eb = jax_bits32(ke0, ke1, (uint32_t)tid);
      s_dr[tid] = (0.1f >= bits_to_unit(eb)) ? 1 : 0;
    }
    __syncthreads();

    f32x4 acc0[2][2] = {};
    f32x4 acc1[2][2] = {};
    const int v0a = (2 * blk) * 64;
    const int v0b = v0a + 64;

    for (int k0 = 0; k0 < Hn; k0 += 32) {
      bf16x8 a0[2], a1[2], a2[2];
#pragma unroll
      for (int mi = 0; mi < 2; mi++) {
        const u16* hp = hsCur + (size_t)(wm + mi * 16 + lr) * Hn + k0 + lg * 8;
        a0[mi] = *(const bf16x8*)(hp);
        a1[mi] = *(const bf16x8*)(hp + Bn * Hn);
        a2[mi] = *(const bf16x8*)(hp + 2 * Bn * Hn);
      }
      bf16x8 s0b0[2], s0b1[2], s0b2[2], s1b0[2], s1b1[2], s1b2[2];
#pragma unroll
      for (int ni = 0; ni < 2; ni++) {
        const float* sp = w_out + (size_t)(v0a + wn + ni * 16 + lr) * Hn + k0 + lg * 8;
        const float4 x0 = *(const float4*)sp;
        const float4 x1 = *(const float4*)(sp + 4);
        split3_frag(x0, x1, 0xFFFFFFFFu, s0b0[ni], s0b1[ni], s0b2[ni]);
      }
#pragma unroll
      for (int ni = 0; ni < 2; ni++) {
        const float* sp = w_out + (size_t)(v0b + wn + ni * 16 + lr) * Hn + k0 + lg * 8;
        const float4 x0 = *(const float4*)sp;
        const float4 x1 = *(const float4*)(sp + 4);
        split3_frag(x0, x1, 0xFFFFFFFFu, s1b0[ni], s1b1[ni], s1b2[ni]);
      }
#pragma unroll
      for (int mi = 0; mi < 2; mi++)
#pragma unroll
        for (int ni = 0; ni < 2; ni++) {
          acc0[mi][ni] = mfma6(a0[mi], a1[mi], a2[mi],
                               s0b0[ni], s0b1[ni], s0b2[ni], acc0[mi][ni]);
          acc1[mi][ni] = mfma6(a0[mi], a1[mi], a2[mi],
                               s1b0[ni], s1b1[ni], s1b2[ni], acc1[mi][ni]);
        }
    }

    // bias + publish per-strip partials (acc mutated: bias included)
    auto publish = [&](f32x4 (&acc)[2][2], const int strip, const int v0) {
      float bias[2];
#pragma unroll
      for (int ni = 0; ni < 2; ni++) bias[ni] = b_out[v0 + wn + ni * 16 + lr];
#pragma unroll
      for (int mi = 0; mi < 2; mi++)
#pragma unroll
        for (int ni = 0; ni < 2; ni++)
#pragma unroll
          for (int r = 0; r < 4; r++) acc[mi][ni][r] += bias[ni];

#pragma unroll
      for (int mi = 0; mi < 2; mi++) {
#pragma unroll
        for (int r = 0; r < 4; r++) {
          const int brow = wm + mi * 16 + lg * 4 + r;
          const int dr = s_dr[brow];
          const int vA = v0 + wn + lr, vB = vA + 16;
          const float zA = acc[mi][0][r], zB = acc[mi][1][r];
          float mz = fmaxf(zA, zB);
#pragma unroll
          for (int off = 1; off < 16; off <<= 1)
            mz = fmaxf(mz, __shfl_xor(mz, off, 64));
          float sz = expf(zA - mz) + expf(zB - mz);
#pragma unroll
          for (int off = 1; off < 16; off <<= 1) sz += __shfl_xor(sz, off, 64);
          const uint32_t bA = jax_bits32(kg0, kg1, (uint32_t)(brow * Vn + vA));
          const uint32_t bB = jax_bits32(kg0, kg1, (uint32_t)(brow * Vn + vB));
          const float uA = fmaxf(1e-9f, bits_to_unit(bA) + 1e-9f);
          const float uB = fmaxf(1e-9f, bits_to_unit(bB) + 1e-9f);
          const float glA = logf(-logf(uA));
          const float glB = logf(-logf(uB));
          const float sA = (dr ? LU : zA) - glA;
          const float sB = (dr ? LU : zB) - glB;
          float bs; int bv; float bz;
          if (sB > sA) { bs = sB; bv = vB; bz = zB; }
          else         { bs = sA; bv = vA; bz = zA; }
#pragma unroll
          for (int off = 1; off < 16; off <<= 1) {
            const float so = __shfl_xor(bs, off, 64);
            const int vo = __shfl_xor(bv, off, 64);
            const float zo = __shfl_xor(bz, off, 64);
            if (so > bs || (so == bs && vo < bv)) { bs = so; bv = vo; bz = zo; }
          }
          if (lr == 0) {
            ldsM[brow][w & 1] = mz; ldsS[brow][w & 1] = sz;
            ldsBS[brow][w & 1] = bs; ldsBV[brow][w & 1] = bv;
            ldsBZ[brow][w & 1] = bz;
          }
        }
      }
      __syncthreads();
      if (tid < 64) {
        const float m0 = ldsM[tid][0], m1 = ldsM[tid][1];
        const float mm = fmaxf(m0, m1);
        const float ss = ldsS[tid][0] * expf(m0 - mm) + ldsS[tid][1] * expf(m1 - mm);
        float bs = ldsBS[tid][0]; int bv = ldsBV[tid][0]; float bz = ldsBZ[tid][0];
        if (ldsBS[tid][1] > bs || (ldsBS[tid][1] == bs && ldsBV[tid][1] < bv)) {
          bs = ldsBS[tid][1]; bv = ldsBV[tid][1]; bz = ldsBZ[tid][1];
        }
        const int o = strip * 64 + tid;
        pM[o] = mm; pS[o] = ss; pBS[o] = bs; pBV[o] = bv; pBZ[o] = bz;
      }
      __syncthreads();
    };
    publish(acc0, 2 * blk, v0a);
    publish(acc1, 2 * blk + 1, v0b);

    gridbar(bar, (++syncno) * NBLK);   // partials ready

    // ================= phase W =================
    // row stats (every block): 4 lanes per row, 125 strips each
    {
      const int row = tid >> 2, q = tid & 3;
      float m = -INFINITY, S = 0.f;
      for (int i = 0; i < NSTRIP / 4; i++) {
        const int s = q * (NSTRIP / 4) + i;
        const float m2 = pM[s * 64 + row], s2 = pS[s * 64 + row];
        const float mn = fmaxf(m, m2);
        S = S * expf(m - mn) + s2 * expf(m2 - mn);
        m = mn;
      }
#pragma unroll
      for (int off = 1; off <= 2; off <<= 1) {
        const float mo = __shfl_xor(m, off, 64);
        const float so = __shfl_xor(S, off, 64);
        const float mn = fmaxf(m, mo);
        S = S * expf(m - mn) + so * expf(mo - mn);
        m = mn;
      }
      const float l = logf(S);
      if (q == 0) { s_m[row] = m; s_l[row] = l; }

      // best-reduce: gru blocks (for next sampled); block0 writes outputs
      if (isGru) {
        float bs = -INFINITY; int bv = Vn; float bz = 0.f;
        for (int i = 0; i < NSTRIP / 4; i++) {
          const int s = q * (NSTRIP / 4) + i;
          const int o = s * 64 + row;
          const float b2 = pBS[o]; const int v2 = pBV[o];
          if (b2 > bs || (b2 == bs && v2 < bv)) {
            bs = b2; bv = v2;
            if (blk == 0) bz = pBZ[o];
          }
        }
#pragma unroll
        for (int off = 1; off <= 2; off <<= 1) {
          const float bo = __shfl_xor(bs, off, 64);
          const int vo = __shfl_xor(bv, off, 64);
          const float zo = __shfl_xor(bz, off, 64);
          if (bo > bs || (bo == bs && vo < bv)) { bs = bo; bv = vo; bz = zo; }
        }
        if (q == 0) {
          s_smp[row] = bv;
          if (blk == 0) {
            out[OUT_SAMP + row * Tn + t] = (float)bv;
            const float d = (bz - m) - l;
            out[OUT_LOGP + row * Tn + t] = d;
            const float onp = fminf(fmaxf(expf(d), 1e-8f), 1.0f);
            const float offp =
                fminf(fmaxf(expf(s_dr[row] ? LU : d), 1e-8f), 1.0f);
            out[OUT_CORR + row * Tn + t] = onp / offp;
          }
        }
      }
    }
    __syncthreads();

    // normalize register tiles, write dist ONCE, probs columns
    auto finalize = [&](f32x4 (&acc)[2][2], const int v0) {
      float ce0 = 0.f, ce1 = 0.f;
#pragma unroll
      for (int mi = 0; mi < 2; mi++)
#pragma unroll
        for (int r = 0; r < 4; r++) {
          const int brow = wm + mi * 16 + lg * 4 + r;
          const float m = s_m[brow], l = s_l[brow];
          const float d0 = (acc[mi][0][r] - m) - l;
          const float d1 = (acc[mi][1][r] - m) - l;
          out[OUT_DIST + (size_t)(brow * Tn + t) * Vn + v0 + wn + lr] = d0;
          out[OUT_DIST + (size_t)(brow * Tn + t) * Vn + v0 + wn + 16 + lr] = d1;
          ce0 += expf(d0);
          ce1 += expf(d1);
        }
#pragma unroll
      for (int off = 16; off <= 32; off <<= 1) {
        ce0 += __shfl_xor(ce0, off, 64);
        ce1 += __shfl_xor(ce1, off, 64);
      }
      if (lg == 0) {
        pc[w >> 1][wn + lr] = ce0;
        pc[w >> 1][wn + 16 + lr] = ce1;
      }
      __syncthreads();
      if (tid < 64)
        out[OUT_PROB + (size_t)t * Vn + v0 + tid] =
            (pc[0][tid] + pc[1][tid]) * 0.015625f;
      __syncthreads();
    };
    finalize(acc0, v0a);
    finalize(acc1, v0b);
    // loop wraps: gru blocks use fresh s_smp in A(t+1); partials protected by
    // the next gridbar before being overwritten in B(t+1).
  }
}

// ---------------- host ----------------
extern "C" void kernel_launch(void* const* d_in, const int* in_sizes, int n_in,
                              void* d_out, int out_size, void* d_ws, size_t ws_size,
                              hipStream_t stream) {
  const float* emb   = (const float*)d_in[0];
  const float* w_ih  = (const float*)d_in[1];
  const float* b_ih  = (const float*)d_in[2];
  const float* w_hh  = (const float*)d_in[3];
  const float* b_hh  = (const float*)d_in[4];
  const float* w_out = (const float*)d_in[5];
  const float* b_out = (const float*)d_in[6];
  float* out = (float*)d_out;
  float* ws  = (float*)d_ws;

  float* hT  = ws + WS_HT;
  u16*   hs  = (u16*)(ws + WS_HS);
  float* pM  = ws + WS_PM;
  float* pS  = ws + WS_PS;
  float* pBS = ws + WS_PBS;
  int*   pBV = (int*)(ws + WS_PBV);
  float* pBZ = ws + WS_PBZ;
  int*   bar = (int*)(ws + WS_BAR);

  init_k<<<(3 * Bn * Hn + 255) / 256, 256, 0, stream>>>(hT, (uint32_t*)hs, bar);
  mega<<<NBLK, 256, 0, stream>>>(emb, w_ih, b_ih, w_hh, b_hh, w_out, b_out,
                                 out, hT, hs, pM, pS, pBS, pBV, pBZ, bar);
}